// Round 1
// baseline (181.486 us; speedup 1.0000x reference)
//
#include <hip/hip_runtime.h>

#define DIM   1024
#define NQKV  3072
#define SEQ   2048
#define HEADS 16
#define DHEAD 64
#define M_TOT 4096   // batch(2) * seq(2048)

typedef __bf16 bf16;
typedef __bf16 bf16x8 __attribute__((ext_vector_type(8)));
typedef float  f32x4  __attribute__((ext_vector_type(4)));

typedef const __attribute__((address_space(1))) unsigned int gu32;
typedef __attribute__((address_space(3))) unsigned int su32;

static __device__ __forceinline__ unsigned short f2b(float f) {
    bf16 h = (bf16)f;
    return __builtin_bit_cast(unsigned short, h);
}

// ---------------- kernel 1: fused prep (cast x -> bf16 | transpose+scale W) ----------------
#define CAST_BLOCKS (M_TOT * DIM / (256 * 4))
__global__ void prep_kernel(const float* __restrict__ x,
                            unsigned short* __restrict__ xb,
                            const float* __restrict__ W,
                            unsigned short* __restrict__ Wt) {
    __shared__ float tile[32][33];
    const int id  = blockIdx.x;
    const int tid = threadIdx.x;
    if (id < CAST_BLOCKS) {
        int i = (id * 256 + tid) * 4;
        float4 v = *(const float4*)(x + i);
        ushort4 o;
        o.x = f2b(v.x); o.y = f2b(v.y); o.z = f2b(v.z); o.w = f2b(v.w);
        *(ushort4*)(xb + i) = o;
    } else {
        int t  = id - CAST_BLOCKS;
        int nb = t % (NQKV / 32);
        int kb = t / (NQKV / 32);
        int tx = tid & 31, ty0 = tid >> 5;
        for (int ty = ty0; ty < 32; ty += 8)
            tile[ty][tx] = W[(size_t)(kb*32 + ty)*NQKV + nb*32 + tx];
        __syncthreads();
        for (int ty = ty0; ty < 32; ty += 8) {
            int n = nb*32 + ty;
            float s = (n < 1024) ? 0.18033688f : 1.0f;   // 0.125 * log2(e)
            Wt[(size_t)n*DIM + kb*32 + tx] = f2b(tile[tx][ty] * s);
        }
    }
}

// ---------------- kernel 2: QKV GEMM, LDS-restaged coalesced epilogue ----------------
#define LDC 136
__global__ __launch_bounds__(256) void qkv_gemm_kernel(
    const unsigned short* __restrict__ A,
    const unsigned short* __restrict__ Bt,
    unsigned short* __restrict__ Qw,
    unsigned short* __restrict__ Kw,
    unsigned short* __restrict__ Vtw)
{
    __shared__ __align__(16) unsigned char smem[128 * LDC * 2];   // 34816 B
    unsigned short* As = (unsigned short*)smem;
    unsigned short* Bs = (unsigned short*)(smem + 16384);
    unsigned short* Cs = (unsigned short*)smem;

    const int tid  = threadIdx.x;
    const int m0   = blockIdx.y * 128;
    const int n0   = blockIdx.x * 128;
    const int w    = tid >> 6;
    const int lane = tid & 63;
    const int l16  = lane & 15;
    const int quad = lane >> 4;
    const int wm   = (w >> 1) * 64;
    const int wn   = (w & 1) * 64;
    const int srow = lane >> 3;
    const int scol = (lane & 7) * 8;

    f32x4 acc[4][4];
    const f32x4 fzero = {0.f, 0.f, 0.f, 0.f};
    for (int i = 0; i < 4; i++)
        for (int j = 0; j < 4; j++) acc[i][j] = fzero;

    const unsigned short* Ag = A  + (size_t)(m0 + w * 32 + srow) * DIM + scol;
    const unsigned short* Bg = Bt + (size_t)(n0 + w * 32 + srow) * DIM + scol;

    for (int kt = 0; kt < DIM; kt += 64) {
        #pragma unroll
        for (int j = 0; j < 4; j++) {
            __builtin_amdgcn_global_load_lds((gu32*)(Ag + kt + (size_t)j * 8 * DIM),
                                             (su32*)&As[(w * 32 + j * 8) * 64], 16, 0, 0);
            __builtin_amdgcn_global_load_lds((gu32*)(Bg + kt + (size_t)j * 8 * DIM),
                                             (su32*)&Bs[(w * 32 + j * 8) * 64], 16, 0, 0);
        }
        __syncthreads();
        #pragma unroll
        for (int s = 0; s < 2; s++) {
            bf16x8 af[4], bfr[4];
            #pragma unroll
            for (int i = 0; i < 4; i++) {
                af[i]  = *(const bf16x8*)(&As[(wm + i * 16 + l16) * 64 + s * 32 + quad * 8]);
                bfr[i] = *(const bf16x8*)(&Bs[(wn + i * 16 + l16) * 64 + s * 32 + quad * 8]);
            }
            #pragma unroll
            for (int i = 0; i < 4; i++)
                #pragma unroll
                for (int j = 0; j < 4; j++)
                    acc[i][j] = __builtin_amdgcn_mfma_f32_16x16x32_bf16(af[i], bfr[j], acc[i][j], 0, 0, 0);
        }
        __syncthreads();
    }

    const int part = n0 >> 10;
    const int h0   = (n0 & 1023) >> 6;
    const int b    = m0 >> 11;
    const int np0  = m0 & 2047;

    if (part < 2) {
        #pragma unroll
        for (int i = 0; i < 4; i++)
            #pragma unroll
            for (int j = 0; j < 4; j++)
                #pragma unroll
                for (int r = 0; r < 4; r++)
                    Cs[(wm + i * 16 + quad * 4 + r) * LDC + wn + j * 16 + l16] = f2b(acc[i][j][r]);
        __syncthreads();
        unsigned short* dst = (part == 0) ? Qw : Kw;
        #pragma unroll
        for (int pass = 0; pass < 8; pass++) {
            int mi = pass * 16 + (tid >> 4);
            int ci = (tid & 15) * 8;
            uint4 v = *(const uint4*)&Cs[mi * LDC + ci];
            int bh = b * HEADS + h0 + (ci >> 6);
            *(uint4*)&dst[((size_t)bh * SEQ + np0 + mi) * DHEAD + (ci & 63)] = v;
        }
    } else {
        #pragma unroll
        for (int i = 0; i < 4; i++)
            #pragma unroll
            for (int j = 0; j < 4; j++) {
                ushort4 pk;
                pk.x = f2b(acc[i][j][0]); pk.y = f2b(acc[i][j][1]);
                pk.z = f2b(acc[i][j][2]); pk.w = f2b(acc[i][j][3]);
                *(ushort4*)&Cs[(wn + j * 16 + l16) * LDC + wm + i * 16 + quad * 4] = pk;
            }
        __syncthreads();
        #pragma unroll
        for (int pass = 0; pass < 8; pass++) {
            int ci = pass * 16 + (tid >> 4);
            int mi = (tid & 15) * 8;
            uint4 v = *(const uint4*)&Cs[ci * LDC + mi];
            int bh = b * HEADS + h0 + (ci >> 6);
            *(uint4*)&Vtw[((size_t)bh * DHEAD + (ci & 63)) * SEQ + np0 + mi] = v;
        }
    }
}

// ---------------- kernel 3: flash attention + residual ----------------
// R4 structure (64-key tiles, sacc[4] — the 128-key/sacc[8] variants spill to
// scratch: R5/R6 WRITE_SIZE 277/573 MB). Key-permuted S^T makes QK C-regs the
// PV A-frags in-register; denominator on the MFMA pipe via ones-vector.
//
// R7: Ks stored under the READ permutation (physical row = ki*16 + l16) so the
// QK ds_read_b128 walks stride-1 rows -> bank-group (l16+4s+quad)%8, balanced.
// The old layout read rows {0-3,8-11,16-19,24-27} (row%8 in {0..3}) -> group
// histogram {4,8,12,16,12,8,4,0} = 8 extra cyc/read; counter showed exactly
// 8 reads * 8 cyc * 131072 wave-iters = 2^23 conflict cycles. Write side
// ((4(w&3) + (lane>>3)&3 + lane&7)%8) stays balanced. Values per lane are
// bit-identical; only LDS addresses changed.
#define LDK 72
__global__ __launch_bounds__(256) void attn_kernel(
    const unsigned short* __restrict__ Qw,
    const unsigned short* __restrict__ Kw,
    const unsigned short* __restrict__ Vtw,
    const float* __restrict__ x,
    float* __restrict__ out)
{
    __shared__ __align__(16) unsigned short Ks[64 * LDK];   // [perm key][d]
    __shared__ __align__(16) unsigned short Vs[64 * LDK];   // V^T: [d][key]
    const int id  = blockIdx.x;
    const int qt  = id >> 5;
    const int bh  = ((id & 7) << 2) | ((id >> 3) & 3);      // 4 bh per XCD
    const int tid = threadIdx.x;
    const int w   = tid >> 6, lane = tid & 63;
    const int l16 = lane & 15, quad = lane >> 4;

    const unsigned short* Qbase = Qw + ((size_t)bh * SEQ + qt * 64 + w * 16 + l16) * DHEAD;
    bf16x8 qf[2];
    qf[0] = *(const bf16x8*)(Qbase + quad * 8);
    qf[1] = *(const bf16x8*)(Qbase + 32 + quad * 8);

    bf16x8 ones;
    #pragma unroll
    for (int j = 0; j < 8; j++) ones[j] = (bf16)1.0f;

    f32x4 o[4], dsum;
    const f32x4 fzero = {0.f, 0.f, 0.f, 0.f};
    #pragma unroll
    for (int d = 0; d < 4; d++) o[d] = fzero;
    dsum = fzero;

    const unsigned short* Kg = Kw  + (size_t)bh * SEQ * DHEAD;
    const unsigned short* Vg = Vtw + (size_t)bh * DHEAD * SEQ;

    const int r0 = tid >> 3, c0 = (tid & 7) * 8;
    // physical Ks row for logical key r0: p = ki*16 + l16,
    // ki = (r0>>2)&1 (r0<32), l16 = 4*((r0>>3)&3) + (r0&3); p(r0+32) = p(r0)+32
    const int pr0 = ((r0 >> 2) & 1) * 16 + ((r0 >> 3) & 3) * 4 + (r0 & 3);
    uint4 kreg0 = *(const uint4*)(Kg + (size_t)r0 * DHEAD + c0);
    uint4 kreg1 = *(const uint4*)(Kg + (size_t)(r0 + 32) * DHEAD + c0);
    uint4 vreg0 = *(const uint4*)(Vg + (size_t)r0 * SEQ + c0);
    uint4 vreg1 = *(const uint4*)(Vg + (size_t)(r0 + 32) * SEQ + c0);

    for (int t = 0; t < SEQ / 64; t++) {
        __syncthreads();
        *(uint4*)&Ks[pr0 * LDK + c0]        = kreg0;
        *(uint4*)&Ks[(pr0 + 32) * LDK + c0] = kreg1;
        *(uint4*)&Vs[r0 * LDK + c0]         = vreg0;
        *(uint4*)&Vs[(r0 + 32) * LDK + c0]  = vreg1;
        int kvn = ((t + 1) & (SEQ / 64 - 1)) * 64;
        kreg0 = *(const uint4*)(Kg + (size_t)(kvn + r0) * DHEAD + c0);
        kreg1 = *(const uint4*)(Kg + (size_t)(kvn + r0 + 32) * DHEAD + c0);
        vreg0 = *(const uint4*)(Vg + (size_t)r0 * SEQ + kvn + c0);
        vreg1 = *(const uint4*)(Vg + (size_t)(r0 + 32) * SEQ + kvn + c0);
        __syncthreads();

        // S^T = K_perm · Q^T   (Ks physical row = ki*16 + l16, conflict-free)
        f32x4 sacc[4];
        #pragma unroll
        for (int ki = 0; ki < 4; ki++) sacc[ki] = fzero;
        #pragma unroll
        for (int s = 0; s < 2; s++)
            #pragma unroll
            for (int ki = 0; ki < 4; ki++) {
                bf16x8 kf = *(const bf16x8*)(
                    &Ks[(ki * 16 + l16) * LDK + s * 32 + quad * 8]);
                sacc[ki] = __builtin_amdgcn_mfma_f32_16x16x32_bf16(kf, qf[s], sacc[ki], 0, 0, 0);
            }

        // p = exp2(s); C-regs are the PV A-frags; denominator via ones-MFMA
        bf16x8 pf[2];
        #pragma unroll
        for (int s = 0; s < 2; s++)
            #pragma unroll
            for (int half = 0; half < 2; half++) {
                int ki = 2 * s + half;
                #pragma unroll
                for (int r = 0; r < 4; r++)
                    pf[s][half * 4 + r] = (bf16)__builtin_amdgcn_exp2f(sacc[ki][r]);
            }

        #pragma unroll
        for (int s = 0; s < 2; s++) {
            dsum = __builtin_amdgcn_mfma_f32_16x16x32_bf16(pf[s], ones, dsum, 0, 0, 0);
            #pragma unroll
            for (int d = 0; d < 4; d++) {
                bf16x8 vf = *(const bf16x8*)(&Vs[(d * 16 + l16) * LDK + s * 32 + quad * 8]);
                o[d] = __builtin_amdgcn_mfma_f32_16x16x32_bf16(pf[s], vf, o[d], 0, 0, 0);
            }
        }
    }

    // dsum[r] = denominator of query quad*4+r (replicated across l16 lanes)
    float lr[4];
    #pragma unroll
    for (int r = 0; r < 4; r++) lr[r] = __builtin_amdgcn_rcpf(dsum[r]);

    const int b = bh >> 4, h = bh & 15;
    #pragma unroll
    for (int di = 0; di < 4; di++)
        #pragma unroll
        for (int r = 0; r < 4; r++) {
            int np  = qt * 64 + w * 16 + quad * 4 + r;
            int col = h * 64 + di * 16 + l16;
            size_t g = ((size_t)(b * SEQ + np)) * DIM + col;
            out[g] = o[di][r] * lr[r] + x[g];
        }
}

extern "C" void kernel_launch(void* const* d_in, const int* in_sizes, int n_in,
                              void* d_out, int out_size, void* d_ws, size_t ws_size,
                              hipStream_t stream) {
    const float* x  = (const float*)d_in[0];   // [2,2048,1024]
    const float* Wq = (const float*)d_in[1];   // [1024,3072]
    float* out = (float*)d_out;

    unsigned short* xb = (unsigned short*)d_ws;                  // [4096][1024]
    unsigned short* Wt = xb + (size_t)M_TOT * DIM;               // [3072][1024]
    unsigned short* Qw = Wt + (size_t)NQKV * DIM;                // [32][2048][64]
    unsigned short* Kw = Qw + (size_t)32 * SEQ * DHEAD;          // [32][2048][64]
    unsigned short* Vt = Kw + (size_t)32 * SEQ * DHEAD;          // [32][64][2048]

    prep_kernel<<<CAST_BLOCKS + (NQKV / 32) * (DIM / 32), 256, 0, stream>>>(x, xb, Wq, Wt);
    qkv_gemm_kernel<<<dim3(NQKV / 128, M_TOT / 128), 256, 0, stream>>>(xb, Wt, Qw, Kw, Vt);
    attn_kernel<<<(SEQ / 64) * 32, 256, 0, stream>>>(Qw, Kw, Vt, x, out);
}

// Round 2
// 177.537 us; speedup vs baseline: 1.0222x; 1.0222x over previous
//
#include <hip/hip_runtime.h>

#define DIM   1024
#define NQKV  3072
#define SEQ   2048
#define HEADS 16
#define DHEAD 64
#define M_TOT 4096   // batch(2) * seq(2048)

typedef __bf16 bf16;
typedef __bf16 bf16x8 __attribute__((ext_vector_type(8)));
typedef float  f32x4  __attribute__((ext_vector_type(4)));

typedef const __attribute__((address_space(1))) unsigned int gu32;
typedef __attribute__((address_space(3))) unsigned int su32;

static __device__ __forceinline__ unsigned short f2b(float f) {
    bf16 h = (bf16)f;
    return __builtin_bit_cast(unsigned short, h);
}

// ---------------- kernel 1: fused prep (cast x -> bf16 | transpose+scale W) ----------------
// R8: transpose moved to 64x64 tiles with float4 global reads (256B/row segments,
// full 128B-line utilization) and single uint4 (8-ushort) global writes per lane.
// Old 32x32 version read 128B rows at 256B/wave-instr.
#define CAST_BLOCKS (M_TOT * DIM / (256 * 4))
#define TR_NB (NQKV / 64)   // 48
__global__ void prep_kernel(const float* __restrict__ x,
                            unsigned short* __restrict__ xb,
                            const float* __restrict__ W,
                            unsigned short* __restrict__ Wt) {
    __shared__ float tile[64][65];   // [n_local][k_local], padded
    const int id  = blockIdx.x;
    const int tid = threadIdx.x;
    if (id < CAST_BLOCKS) {
        int i = (id * 256 + tid) * 4;
        float4 v = *(const float4*)(x + i);
        ushort4 o;
        o.x = f2b(v.x); o.y = f2b(v.y); o.z = f2b(v.z); o.w = f2b(v.w);
        *(ushort4*)(xb + i) = o;
    } else {
        int t  = id - CAST_BLOCKS;
        int nb = t % TR_NB;
        int kb = t / TR_NB;          // 0..15
        #pragma unroll
        for (int p = 0; p < 4; p++) {
            int kl = p * 16 + (tid >> 4);        // 0..63
            int nl = (tid & 15) * 4;             // 0..60
            float4 v = *(const float4*)&W[(size_t)(kb * 64 + kl) * NQKV + nb * 64 + nl];
            tile[nl + 0][kl] = v.x;
            tile[nl + 1][kl] = v.y;
            tile[nl + 2][kl] = v.z;
            tile[nl + 3][kl] = v.w;
        }
        __syncthreads();
        #pragma unroll
        for (int p = 0; p < 2; p++) {
            int nl = p * 32 + (tid >> 3);        // 0..63
            int k8 = (tid & 7) * 8;              // 0..56
            int n  = nb * 64 + nl;
            float s = (n < 1024) ? 0.18033688f : 1.0f;   // 0.125 * log2(e)
            float4 a = *(const float4*)&tile[nl][k8];
            float4 b = *(const float4*)&tile[nl][k8 + 4];
            ushort4 o0, o1;
            o0.x = f2b(a.x * s); o0.y = f2b(a.y * s); o0.z = f2b(a.z * s); o0.w = f2b(a.w * s);
            o1.x = f2b(b.x * s); o1.y = f2b(b.y * s); o1.z = f2b(b.z * s); o1.w = f2b(b.w * s);
            uint4 pk;
            pk.x = ((unsigned)o0.y << 16) | o0.x;
            pk.y = ((unsigned)o0.w << 16) | o0.z;
            pk.z = ((unsigned)o1.y << 16) | o1.x;
            pk.w = ((unsigned)o1.w << 16) | o1.z;
            *(uint4*)&Wt[(size_t)n * DIM + kb * 64 + k8] = pk;
        }
    }
}

// ---------------- kernel 2: QKV GEMM, LDS-restaged coalesced epilogue ----------------
#define LDC 136
__global__ __launch_bounds__(256) void qkv_gemm_kernel(
    const unsigned short* __restrict__ A,
    const unsigned short* __restrict__ Bt,
    unsigned short* __restrict__ Qw,
    unsigned short* __restrict__ Kw,
    unsigned short* __restrict__ Vtw)
{
    __shared__ __align__(16) unsigned char smem[128 * LDC * 2];   // 34816 B
    unsigned short* As = (unsigned short*)smem;
    unsigned short* Bs = (unsigned short*)(smem + 16384);
    unsigned short* Cs = (unsigned short*)smem;

    const int tid  = threadIdx.x;
    const int m0   = blockIdx.y * 128;
    const int n0   = blockIdx.x * 128;
    const int w    = tid >> 6;
    const int lane = tid & 63;
    const int l16  = lane & 15;
    const int quad = lane >> 4;
    const int wm   = (w >> 1) * 64;
    const int wn   = (w & 1) * 64;
    const int srow = lane >> 3;
    const int scol = (lane & 7) * 8;

    f32x4 acc[4][4];
    const f32x4 fzero = {0.f, 0.f, 0.f, 0.f};
    for (int i = 0; i < 4; i++)
        for (int j = 0; j < 4; j++) acc[i][j] = fzero;

    const unsigned short* Ag = A  + (size_t)(m0 + w * 32 + srow) * DIM + scol;
    const unsigned short* Bg = Bt + (size_t)(n0 + w * 32 + srow) * DIM + scol;

    for (int kt = 0; kt < DIM; kt += 64) {
        #pragma unroll
        for (int j = 0; j < 4; j++) {
            __builtin_amdgcn_global_load_lds((gu32*)(Ag + kt + (size_t)j * 8 * DIM),
                                             (su32*)&As[(w * 32 + j * 8) * 64], 16, 0, 0);
            __builtin_amdgcn_global_load_lds((gu32*)(Bg + kt + (size_t)j * 8 * DIM),
                                             (su32*)&Bs[(w * 32 + j * 8) * 64], 16, 0, 0);
        }
        __syncthreads();
        #pragma unroll
        for (int s = 0; s < 2; s++) {
            bf16x8 af[4], bfr[4];
            #pragma unroll
            for (int i = 0; i < 4; i++) {
                af[i]  = *(const bf16x8*)(&As[(wm + i * 16 + l16) * 64 + s * 32 + quad * 8]);
                bfr[i] = *(const bf16x8*)(&Bs[(wn + i * 16 + l16) * 64 + s * 32 + quad * 8]);
            }
            #pragma unroll
            for (int i = 0; i < 4; i++)
                #pragma unroll
                for (int j = 0; j < 4; j++)
                    acc[i][j] = __builtin_amdgcn_mfma_f32_16x16x32_bf16(af[i], bfr[j], acc[i][j], 0, 0, 0);
        }
        __syncthreads();
    }

    const int part = n0 >> 10;
    const int h0   = (n0 & 1023) >> 6;
    const int b    = m0 >> 11;
    const int np0  = m0 & 2047;

    if (part < 2) {
        #pragma unroll
        for (int i = 0; i < 4; i++)
            #pragma unroll
            for (int j = 0; j < 4; j++)
                #pragma unroll
                for (int r = 0; r < 4; r++)
                    Cs[(wm + i * 16 + quad * 4 + r) * LDC + wn + j * 16 + l16] = f2b(acc[i][j][r]);
        __syncthreads();
        unsigned short* dst = (part == 0) ? Qw : Kw;
        #pragma unroll
        for (int pass = 0; pass < 8; pass++) {
            int mi = pass * 16 + (tid >> 4);
            int ci = (tid & 15) * 8;
            uint4 v = *(const uint4*)&Cs[mi * LDC + ci];
            int bh = b * HEADS + h0 + (ci >> 6);
            *(uint4*)&dst[((size_t)bh * SEQ + np0 + mi) * DHEAD + (ci & 63)] = v;
        }
    } else {
        #pragma unroll
        for (int i = 0; i < 4; i++)
            #pragma unroll
            for (int j = 0; j < 4; j++) {
                ushort4 pk;
                pk.x = f2b(acc[i][j][0]); pk.y = f2b(acc[i][j][1]);
                pk.z = f2b(acc[i][j][2]); pk.w = f2b(acc[i][j][3]);
                *(ushort4*)&Cs[(wn + j * 16 + l16) * LDC + wm + i * 16 + quad * 4] = pk;
            }
        __syncthreads();
        #pragma unroll
        for (int pass = 0; pass < 8; pass++) {
            int ci = pass * 16 + (tid >> 4);
            int mi = (tid & 15) * 8;
            uint4 v = *(const uint4*)&Cs[ci * LDC + mi];
            int bh = b * HEADS + h0 + (ci >> 6);
            *(uint4*)&Vtw[((size_t)bh * DHEAD + (ci & 63)) * SEQ + np0 + mi] = v;
        }
    }
}

// ---------------- kernel 3: flash attention + residual ----------------
// R4 structure (64-key tiles, sacc[4]); key-permuted S^T makes QK C-regs the PV
// A-frags in-register; denominator on the MFMA pipe via ones-vector.
//
// R8: SQ_LDS_BANK_CONFLICT is exactly 4 counts per ds_read_b128 (2^23 =
// 16 reads * 131072 wave-iters * 4) in BOTH the R6 and R7 layouts -> it's the
// structural b128 baseline, not real conflicts. The real ~30% stall is the
// 2-barrier-per-tile staging. Fix: LDS double-buffer (Ks/Vs x2, 36.8KB, still
// 4 blocks/CU), ONE barrier per tile; ds_write of tile t+1 and global loads of
// tile t+2 overlap with compute of tile t.
#define LDK 72
__global__ __launch_bounds__(256) void attn_kernel(
    const unsigned short* __restrict__ Qw,
    const unsigned short* __restrict__ Kw,
    const unsigned short* __restrict__ Vtw,
    const float* __restrict__ x,
    float* __restrict__ out)
{
    __shared__ __align__(16) unsigned short Ks[2][64 * LDK];   // [buf][perm key][d]
    __shared__ __align__(16) unsigned short Vs[2][64 * LDK];   // [buf] V^T: [d][key]
    const int id  = blockIdx.x;
    const int qt  = id >> 5;
    const int bh  = ((id & 7) << 2) | ((id >> 3) & 3);      // 4 bh per XCD
    const int tid = threadIdx.x;
    const int w   = tid >> 6, lane = tid & 63;
    const int l16 = lane & 15, quad = lane >> 4;

    const unsigned short* Qbase = Qw + ((size_t)bh * SEQ + qt * 64 + w * 16 + l16) * DHEAD;
    bf16x8 qf[2];
    qf[0] = *(const bf16x8*)(Qbase + quad * 8);
    qf[1] = *(const bf16x8*)(Qbase + 32 + quad * 8);

    bf16x8 ones;
    #pragma unroll
    for (int j = 0; j < 8; j++) ones[j] = (bf16)1.0f;

    f32x4 o[4], dsum;
    const f32x4 fzero = {0.f, 0.f, 0.f, 0.f};
    #pragma unroll
    for (int d = 0; d < 4; d++) o[d] = fzero;
    dsum = fzero;

    const unsigned short* Kg = Kw  + (size_t)bh * SEQ * DHEAD;
    const unsigned short* Vg = Vtw + (size_t)bh * DHEAD * SEQ;

    const int r0 = tid >> 3, c0 = (tid & 7) * 8;
    // physical Ks row for logical key r0: p = ki*16 + l16 (read-permutation inverse)
    const int pr0 = ((r0 >> 2) & 1) * 16 + ((r0 >> 3) & 3) * 4 + (r0 & 3);

    // prologue: tile 0 -> buf 0 (no barrier needed before first loop barrier)
    uint4 kreg0 = *(const uint4*)(Kg + (size_t)r0 * DHEAD + c0);
    uint4 kreg1 = *(const uint4*)(Kg + (size_t)(r0 + 32) * DHEAD + c0);
    uint4 vreg0 = *(const uint4*)(Vg + (size_t)r0 * SEQ + c0);
    uint4 vreg1 = *(const uint4*)(Vg + (size_t)(r0 + 32) * SEQ + c0);
    *(uint4*)&Ks[0][pr0 * LDK + c0]        = kreg0;
    *(uint4*)&Ks[0][(pr0 + 32) * LDK + c0] = kreg1;
    *(uint4*)&Vs[0][r0 * LDK + c0]         = vreg0;
    *(uint4*)&Vs[0][(r0 + 32) * LDK + c0]  = vreg1;
    // prefetch tile 1 into regs
    kreg0 = *(const uint4*)(Kg + (size_t)(64 + r0) * DHEAD + c0);
    kreg1 = *(const uint4*)(Kg + (size_t)(64 + r0 + 32) * DHEAD + c0);
    vreg0 = *(const uint4*)(Vg + (size_t)r0 * SEQ + 64 + c0);
    vreg1 = *(const uint4*)(Vg + (size_t)(r0 + 32) * SEQ + 64 + c0);

    for (int t = 0; t < SEQ / 64; t++) {
        const int cur = t & 1, nxt = cur ^ 1;
        __syncthreads();   // writes of tile t (prev iter) visible; readers of t-1 done
        // stage tile t+1 into the buffer nobody reads this iter
        *(uint4*)&Ks[nxt][pr0 * LDK + c0]        = kreg0;
        *(uint4*)&Ks[nxt][(pr0 + 32) * LDK + c0] = kreg1;
        *(uint4*)&Vs[nxt][r0 * LDK + c0]         = vreg0;
        *(uint4*)&Vs[nxt][(r0 + 32) * LDK + c0]  = vreg1;
        // issue global loads of tile t+2 (fly under this iter's compute)
        int kvn = ((t + 2) & (SEQ / 64 - 1)) * 64;
        kreg0 = *(const uint4*)(Kg + (size_t)(kvn + r0) * DHEAD + c0);
        kreg1 = *(const uint4*)(Kg + (size_t)(kvn + r0 + 32) * DHEAD + c0);
        vreg0 = *(const uint4*)(Vg + (size_t)r0 * SEQ + kvn + c0);
        vreg1 = *(const uint4*)(Vg + (size_t)(r0 + 32) * SEQ + kvn + c0);

        // S^T = K_perm · Q^T   (Ks physical row = ki*16 + l16)
        f32x4 sacc[4];
        #pragma unroll
        for (int ki = 0; ki < 4; ki++) sacc[ki] = fzero;
        #pragma unroll
        for (int s = 0; s < 2; s++)
            #pragma unroll
            for (int ki = 0; ki < 4; ki++) {
                bf16x8 kf = *(const bf16x8*)(
                    &Ks[cur][(ki * 16 + l16) * LDK + s * 32 + quad * 8]);
                sacc[ki] = __builtin_amdgcn_mfma_f32_16x16x32_bf16(kf, qf[s], sacc[ki], 0, 0, 0);
            }

        // p = exp2(s); C-regs are the PV A-frags; denominator via ones-MFMA
        bf16x8 pf[2];
        #pragma unroll
        for (int s = 0; s < 2; s++)
            #pragma unroll
            for (int half = 0; half < 2; half++) {
                int ki = 2 * s + half;
                #pragma unroll
                for (int r = 0; r < 4; r++)
                    pf[s][half * 4 + r] = (bf16)__builtin_amdgcn_exp2f(sacc[ki][r]);
            }

        #pragma unroll
        for (int s = 0; s < 2; s++) {
            dsum = __builtin_amdgcn_mfma_f32_16x16x32_bf16(pf[s], ones, dsum, 0, 0, 0);
            #pragma unroll
            for (int d = 0; d < 4; d++) {
                bf16x8 vf = *(const bf16x8*)(&Vs[cur][(d * 16 + l16) * LDK + s * 32 + quad * 8]);
                o[d] = __builtin_amdgcn_mfma_f32_16x16x32_bf16(pf[s], vf, o[d], 0, 0, 0);
            }
        }
    }

    // dsum[r] = denominator of query quad*4+r (replicated across l16 lanes)
    float lr[4];
    #pragma unroll
    for (int r = 0; r < 4; r++) lr[r] = __builtin_amdgcn_rcpf(dsum[r]);

    const int b = bh >> 4, h = bh & 15;
    #pragma unroll
    for (int di = 0; di < 4; di++)
        #pragma unroll
        for (int r = 0; r < 4; r++) {
            int np  = qt * 64 + w * 16 + quad * 4 + r;
            int col = h * 64 + di * 16 + l16;
            size_t g = ((size_t)(b * SEQ + np)) * DIM + col;
            out[g] = o[di][r] * lr[r] + x[g];
        }
}

extern "C" void kernel_launch(void* const* d_in, const int* in_sizes, int n_in,
                              void* d_out, int out_size, void* d_ws, size_t ws_size,
                              hipStream_t stream) {
    const float* x  = (const float*)d_in[0];   // [2,2048,1024]
    const float* Wq = (const float*)d_in[1];   // [1024,3072]
    float* out = (float*)d_out;

    unsigned short* xb = (unsigned short*)d_ws;                  // [4096][1024]
    unsigned short* Wt = xb + (size_t)M_TOT * DIM;               // [3072][1024]
    unsigned short* Qw = Wt + (size_t)NQKV * DIM;                // [32][2048][64]
    unsigned short* Kw = Qw + (size_t)32 * SEQ * DHEAD;          // [32][2048][64]
    unsigned short* Vt = Kw + (size_t)32 * SEQ * DHEAD;          // [32][64][2048]

    prep_kernel<<<CAST_BLOCKS + TR_NB * (DIM / 64), 256, 0, stream>>>(x, xb, Wq, Wt);
    qkv_gemm_kernel<<<dim3(NQKV / 128, M_TOT / 128), 256, 0, stream>>>(xb, Wt, Qw, Kw, Vt);
    attn_kernel<<<(SEQ / 64) * 32, 256, 0, stream>>>(Qw, Kw, Vt, x, out);
}

// Round 3
// 172.851 us; speedup vs baseline: 1.0500x; 1.0271x over previous
//
#include <hip/hip_runtime.h>

#define DIM   1024
#define NQKV  3072
#define SEQ   2048
#define HEADS 16
#define DHEAD 64
#define M_TOT 4096   // batch(2) * seq(2048)

typedef __bf16 bf16;
typedef __bf16 bf16x8 __attribute__((ext_vector_type(8)));
typedef float  f32x4  __attribute__((ext_vector_type(4)));

typedef const __attribute__((address_space(1))) unsigned int gu32;
typedef __attribute__((address_space(3))) unsigned int su32;

static __device__ __forceinline__ unsigned short f2b(float f) {
    bf16 h = (bf16)f;
    return __builtin_bit_cast(unsigned short, h);
}

// ---------------- kernel 1: fused prep (cast x -> bf16 | transpose+scale W) ----------------
// R8: transpose in 64x64 tiles, float4 global reads, uint4 global writes.
#define CAST_BLOCKS (M_TOT * DIM / (256 * 4))
#define TR_NB (NQKV / 64)   // 48
__global__ void prep_kernel(const float* __restrict__ x,
                            unsigned short* __restrict__ xb,
                            const float* __restrict__ W,
                            unsigned short* __restrict__ Wt) {
    __shared__ float tile[64][65];   // [n_local][k_local], padded
    const int id  = blockIdx.x;
    const int tid = threadIdx.x;
    if (id < CAST_BLOCKS) {
        int i = (id * 256 + tid) * 4;
        float4 v = *(const float4*)(x + i);
        ushort4 o;
        o.x = f2b(v.x); o.y = f2b(v.y); o.z = f2b(v.z); o.w = f2b(v.w);
        *(ushort4*)(xb + i) = o;
    } else {
        int t  = id - CAST_BLOCKS;
        int nb = t % TR_NB;
        int kb = t / TR_NB;          // 0..15
        #pragma unroll
        for (int p = 0; p < 4; p++) {
            int kl = p * 16 + (tid >> 4);        // 0..63
            int nl = (tid & 15) * 4;             // 0..60
            float4 v = *(const float4*)&W[(size_t)(kb * 64 + kl) * NQKV + nb * 64 + nl];
            tile[nl + 0][kl] = v.x;
            tile[nl + 1][kl] = v.y;
            tile[nl + 2][kl] = v.z;
            tile[nl + 3][kl] = v.w;
        }
        __syncthreads();
        #pragma unroll
        for (int p = 0; p < 2; p++) {
            int nl = p * 32 + (tid >> 3);        // 0..63
            int k8 = (tid & 7) * 8;              // 0..56
            int n  = nb * 64 + nl;
            float s = (n < 1024) ? 0.18033688f : 1.0f;   // 0.125 * log2(e)
            float4 a = *(const float4*)&tile[nl][k8];
            float4 b = *(const float4*)&tile[nl][k8 + 4];
            ushort4 o0, o1;
            o0.x = f2b(a.x * s); o0.y = f2b(a.y * s); o0.z = f2b(a.z * s); o0.w = f2b(a.w * s);
            o1.x = f2b(b.x * s); o1.y = f2b(b.y * s); o1.z = f2b(b.z * s); o1.w = f2b(b.w * s);
            uint4 pk;
            pk.x = ((unsigned)o0.y << 16) | o0.x;
            pk.y = ((unsigned)o0.w << 16) | o0.z;
            pk.z = ((unsigned)o1.y << 16) | o1.x;
            pk.w = ((unsigned)o1.w << 16) | o1.z;
            *(uint4*)&Wt[(size_t)n * DIM + kb * 64 + k8] = pk;
        }
    }
}

// ---------------- kernel 2: QKV GEMM, LDS-restaged coalesced epilogue ----------------
#define LDC 136
__global__ __launch_bounds__(256) void qkv_gemm_kernel(
    const unsigned short* __restrict__ A,
    const unsigned short* __restrict__ Bt,
    unsigned short* __restrict__ Qw,
    unsigned short* __restrict__ Kw,
    unsigned short* __restrict__ Vtw)
{
    __shared__ __align__(16) unsigned char smem[128 * LDC * 2];   // 34816 B
    unsigned short* As = (unsigned short*)smem;
    unsigned short* Bs = (unsigned short*)(smem + 16384);
    unsigned short* Cs = (unsigned short*)smem;

    const int tid  = threadIdx.x;
    const int m0   = blockIdx.y * 128;
    const int n0   = blockIdx.x * 128;
    const int w    = tid >> 6;
    const int lane = tid & 63;
    const int l16  = lane & 15;
    const int quad = lane >> 4;
    const int wm   = (w >> 1) * 64;
    const int wn   = (w & 1) * 64;
    const int srow = lane >> 3;
    const int scol = (lane & 7) * 8;

    f32x4 acc[4][4];
    const f32x4 fzero = {0.f, 0.f, 0.f, 0.f};
    for (int i = 0; i < 4; i++)
        for (int j = 0; j < 4; j++) acc[i][j] = fzero;

    const unsigned short* Ag = A  + (size_t)(m0 + w * 32 + srow) * DIM + scol;
    const unsigned short* Bg = Bt + (size_t)(n0 + w * 32 + srow) * DIM + scol;

    for (int kt = 0; kt < DIM; kt += 64) {
        #pragma unroll
        for (int j = 0; j < 4; j++) {
            __builtin_amdgcn_global_load_lds((gu32*)(Ag + kt + (size_t)j * 8 * DIM),
                                             (su32*)&As[(w * 32 + j * 8) * 64], 16, 0, 0);
            __builtin_amdgcn_global_load_lds((gu32*)(Bg + kt + (size_t)j * 8 * DIM),
                                             (su32*)&Bs[(w * 32 + j * 8) * 64], 16, 0, 0);
        }
        __syncthreads();
        #pragma unroll
        for (int s = 0; s < 2; s++) {
            bf16x8 af[4], bfr[4];
            #pragma unroll
            for (int i = 0; i < 4; i++) {
                af[i]  = *(const bf16x8*)(&As[(wm + i * 16 + l16) * 64 + s * 32 + quad * 8]);
                bfr[i] = *(const bf16x8*)(&Bs[(wn + i * 16 + l16) * 64 + s * 32 + quad * 8]);
            }
            #pragma unroll
            for (int i = 0; i < 4; i++)
                #pragma unroll
                for (int j = 0; j < 4; j++)
                    acc[i][j] = __builtin_amdgcn_mfma_f32_16x16x32_bf16(af[i], bfr[j], acc[i][j], 0, 0, 0);
        }
        __syncthreads();
    }

    const int part = n0 >> 10;
    const int h0   = (n0 & 1023) >> 6;
    const int b    = m0 >> 11;
    const int np0  = m0 & 2047;

    if (part < 2) {
        #pragma unroll
        for (int i = 0; i < 4; i++)
            #pragma unroll
            for (int j = 0; j < 4; j++)
                #pragma unroll
                for (int r = 0; r < 4; r++)
                    Cs[(wm + i * 16 + quad * 4 + r) * LDC + wn + j * 16 + l16] = f2b(acc[i][j][r]);
        __syncthreads();
        unsigned short* dst = (part == 0) ? Qw : Kw;
        #pragma unroll
        for (int pass = 0; pass < 8; pass++) {
            int mi = pass * 16 + (tid >> 4);
            int ci = (tid & 15) * 8;
            uint4 v = *(const uint4*)&Cs[mi * LDC + ci];
            int bh = b * HEADS + h0 + (ci >> 6);
            *(uint4*)&dst[((size_t)bh * SEQ + np0 + mi) * DHEAD + (ci & 63)] = v;
        }
    } else {
        #pragma unroll
        for (int i = 0; i < 4; i++)
            #pragma unroll
            for (int j = 0; j < 4; j++) {
                ushort4 pk;
                pk.x = f2b(acc[i][j][0]); pk.y = f2b(acc[i][j][1]);
                pk.z = f2b(acc[i][j][2]); pk.w = f2b(acc[i][j][3]);
                *(ushort4*)&Cs[(wn + j * 16 + l16) * LDC + wm + i * 16 + quad * 4] = pk;
            }
        __syncthreads();
        #pragma unroll
        for (int pass = 0; pass < 8; pass++) {
            int ci = pass * 16 + (tid >> 4);
            int mi = (tid & 15) * 8;
            uint4 v = *(const uint4*)&Cs[ci * LDC + mi];
            int bh = b * HEADS + h0 + (ci >> 6);
            *(uint4*)&Vtw[((size_t)bh * DHEAD + (ci & 63)) * SEQ + np0 + mi] = v;
        }
    }
}

// ---------------- kernel 3: flash attention + residual ----------------
// R9: per-CU LDS-pipe accounting showed ~79% of kernel cycles on LDS b128 ops
// (conflict counter = fixed 4/b128-read in every layout -> structural cost;
// dbuf/barrier changes were no-ops). All 4 waves read IDENTICAL K/V frags (no
// `w` in the address) -> 4x redundancy. Fix: 32 queries/wave (block = 128 q),
// each kf/vf LDS read now feeds 2 MFMAs (query-halves qh=0,1); wave-iters
// halve -> total LDS read traffic halves. The two qh dep-chains (QK->exp->PV)
// are independent, adding ILP. Grid 512 = 2 blocks/CU.
#define LDK 72
__global__ __launch_bounds__(256) void attn_kernel(
    const unsigned short* __restrict__ Qw,
    const unsigned short* __restrict__ Kw,
    const unsigned short* __restrict__ Vtw,
    const float* __restrict__ x,
    float* __restrict__ out)
{
    __shared__ __align__(16) unsigned short Ks[2][64 * LDK];   // [buf][perm key][d]
    __shared__ __align__(16) unsigned short Vs[2][64 * LDK];   // [buf] V^T: [d][key]
    const int id  = blockIdx.x;
    const int qt  = id >> 5;                                // 0..15 (128-query tiles)
    const int bh  = ((id & 7) << 2) | ((id >> 3) & 3);      // 4 bh per XCD
    const int tid = threadIdx.x;
    const int w   = tid >> 6, lane = tid & 63;
    const int l16 = lane & 15, quad = lane >> 4;

    const unsigned short* Qb = Qw + ((size_t)bh * SEQ + qt * 128 + w * 32 + l16) * DHEAD;
    bf16x8 qf[2][2];
    #pragma unroll
    for (int qh = 0; qh < 2; qh++) {
        qf[qh][0] = *(const bf16x8*)(Qb + qh * 16 * DHEAD + quad * 8);
        qf[qh][1] = *(const bf16x8*)(Qb + qh * 16 * DHEAD + 32 + quad * 8);
    }

    bf16x8 ones;
    #pragma unroll
    for (int j = 0; j < 8; j++) ones[j] = (bf16)1.0f;

    f32x4 o[2][4], dsum[2];
    const f32x4 fzero = {0.f, 0.f, 0.f, 0.f};
    #pragma unroll
    for (int qh = 0; qh < 2; qh++) {
        #pragma unroll
        for (int d = 0; d < 4; d++) o[qh][d] = fzero;
        dsum[qh] = fzero;
    }

    const unsigned short* Kg = Kw  + (size_t)bh * SEQ * DHEAD;
    const unsigned short* Vg = Vtw + (size_t)bh * DHEAD * SEQ;

    const int r0 = tid >> 3, c0 = (tid & 7) * 8;
    // physical Ks row for logical key r0: p = ki*16 + l16 (read-permutation inverse)
    const int pr0 = ((r0 >> 2) & 1) * 16 + ((r0 >> 3) & 3) * 4 + (r0 & 3);

    // prologue: tile 0 -> buf 0
    uint4 kreg0 = *(const uint4*)(Kg + (size_t)r0 * DHEAD + c0);
    uint4 kreg1 = *(const uint4*)(Kg + (size_t)(r0 + 32) * DHEAD + c0);
    uint4 vreg0 = *(const uint4*)(Vg + (size_t)r0 * SEQ + c0);
    uint4 vreg1 = *(const uint4*)(Vg + (size_t)(r0 + 32) * SEQ + c0);
    *(uint4*)&Ks[0][pr0 * LDK + c0]        = kreg0;
    *(uint4*)&Ks[0][(pr0 + 32) * LDK + c0] = kreg1;
    *(uint4*)&Vs[0][r0 * LDK + c0]         = vreg0;
    *(uint4*)&Vs[0][(r0 + 32) * LDK + c0]  = vreg1;
    // prefetch tile 1 into regs
    kreg0 = *(const uint4*)(Kg + (size_t)(64 + r0) * DHEAD + c0);
    kreg1 = *(const uint4*)(Kg + (size_t)(64 + r0 + 32) * DHEAD + c0);
    vreg0 = *(const uint4*)(Vg + (size_t)r0 * SEQ + 64 + c0);
    vreg1 = *(const uint4*)(Vg + (size_t)(r0 + 32) * SEQ + 64 + c0);

    for (int t = 0; t < SEQ / 64; t++) {
        const int cur = t & 1, nxt = cur ^ 1;
        __syncthreads();
        // stage tile t+1 into the buffer nobody reads this iter
        *(uint4*)&Ks[nxt][pr0 * LDK + c0]        = kreg0;
        *(uint4*)&Ks[nxt][(pr0 + 32) * LDK + c0] = kreg1;
        *(uint4*)&Vs[nxt][r0 * LDK + c0]         = vreg0;
        *(uint4*)&Vs[nxt][(r0 + 32) * LDK + c0]  = vreg1;
        // issue global loads of tile t+2
        int kvn = ((t + 2) & (SEQ / 64 - 1)) * 64;
        kreg0 = *(const uint4*)(Kg + (size_t)(kvn + r0) * DHEAD + c0);
        kreg1 = *(const uint4*)(Kg + (size_t)(kvn + r0 + 32) * DHEAD + c0);
        vreg0 = *(const uint4*)(Vg + (size_t)r0 * SEQ + kvn + c0);
        vreg1 = *(const uint4*)(Vg + (size_t)(r0 + 32) * SEQ + kvn + c0);

        // S^T = K_perm · Q^T for both query halves; each kf read feeds 2 MFMAs
        f32x4 sacc[2][4];
        #pragma unroll
        for (int qh = 0; qh < 2; qh++)
            #pragma unroll
            for (int ki = 0; ki < 4; ki++) sacc[qh][ki] = fzero;
        #pragma unroll
        for (int s = 0; s < 2; s++)
            #pragma unroll
            for (int ki = 0; ki < 4; ki++) {
                bf16x8 kf = *(const bf16x8*)(
                    &Ks[cur][(ki * 16 + l16) * LDK + s * 32 + quad * 8]);
                sacc[0][ki] = __builtin_amdgcn_mfma_f32_16x16x32_bf16(kf, qf[0][s], sacc[0][ki], 0, 0, 0);
                sacc[1][ki] = __builtin_amdgcn_mfma_f32_16x16x32_bf16(kf, qf[1][s], sacc[1][ki], 0, 0, 0);
            }

        // p = exp2(s); C-regs are the PV A-frags; denominator via ones-MFMA
        bf16x8 pf[2][2];
        #pragma unroll
        for (int qh = 0; qh < 2; qh++)
            #pragma unroll
            for (int s = 0; s < 2; s++)
                #pragma unroll
                for (int half = 0; half < 2; half++) {
                    int ki = 2 * s + half;
                    #pragma unroll
                    for (int r = 0; r < 4; r++)
                        pf[qh][s][half * 4 + r] = (bf16)__builtin_amdgcn_exp2f(sacc[qh][ki][r]);
                }

        #pragma unroll
        for (int s = 0; s < 2; s++) {
            dsum[0] = __builtin_amdgcn_mfma_f32_16x16x32_bf16(pf[0][s], ones, dsum[0], 0, 0, 0);
            dsum[1] = __builtin_amdgcn_mfma_f32_16x16x32_bf16(pf[1][s], ones, dsum[1], 0, 0, 0);
            #pragma unroll
            for (int d = 0; d < 4; d++) {
                bf16x8 vf = *(const bf16x8*)(&Vs[cur][(d * 16 + l16) * LDK + s * 32 + quad * 8]);
                o[0][d] = __builtin_amdgcn_mfma_f32_16x16x32_bf16(pf[0][s], vf, o[0][d], 0, 0, 0);
                o[1][d] = __builtin_amdgcn_mfma_f32_16x16x32_bf16(pf[1][s], vf, o[1][d], 0, 0, 0);
            }
        }
    }

    const int b = bh >> 4, h = bh & 15;
    #pragma unroll
    for (int qh = 0; qh < 2; qh++) {
        float lr[4];
        #pragma unroll
        for (int r = 0; r < 4; r++) lr[r] = __builtin_amdgcn_rcpf(dsum[qh][r]);
        #pragma unroll
        for (int di = 0; di < 4; di++)
            #pragma unroll
            for (int r = 0; r < 4; r++) {
                int np  = qt * 128 + w * 32 + qh * 16 + quad * 4 + r;
                int col = h * 64 + di * 16 + l16;
                size_t g = ((size_t)(b * SEQ + np)) * DIM + col;
                out[g] = o[qh][di][r] * lr[r] + x[g];
            }
    }
}

extern "C" void kernel_launch(void* const* d_in, const int* in_sizes, int n_in,
                              void* d_out, int out_size, void* d_ws, size_t ws_size,
                              hipStream_t stream) {
    const float* x  = (const float*)d_in[0];   // [2,2048,1024]
    const float* Wq = (const float*)d_in[1];   // [1024,3072]
    float* out = (float*)d_out;

    unsigned short* xb = (unsigned short*)d_ws;                  // [4096][1024]
    unsigned short* Wt = xb + (size_t)M_TOT * DIM;               // [3072][1024]
    unsigned short* Qw = Wt + (size_t)NQKV * DIM;                // [32][2048][64]
    unsigned short* Kw = Qw + (size_t)32 * SEQ * DHEAD;          // [32][2048][64]
    unsigned short* Vt = Kw + (size_t)32 * SEQ * DHEAD;          // [32][64][2048]

    prep_kernel<<<CAST_BLOCKS + TR_NB * (DIM / 64), 256, 0, stream>>>(x, xb, Wq, Wt);
    qkv_gemm_kernel<<<dim3(NQKV / 128, M_TOT / 128), 256, 0, stream>>>(xb, Wt, Qw, Kw, Vt);
    attn_kernel<<<(SEQ / 128) * 32, 256, 0, stream>>>(Qw, Kw, Vt, x, out);
}